// Round 2
// baseline (1282.779 us; speedup 1.0000x reference)
//
#include <hip/hip_runtime.h>

// Problem constants (from reference)
#define NB 2048                 // buckets per layer (B)
#define NS 2048                 // spigots per bucket (S)
#define NT 16                   // timesteps
#define SQRT2G 4.4294469f       // sqrt(2*9.81)
#define MHALF_SQRT2G -2.2147234f // -0.5*sqrt(2*9.81)
#define PF 32                   // prefetch depth (iterations)

// ---------------------------------------------------------------------------
// Sequential scan over 2048 spigots of one bucket.
// State: w_i = z_i - h_i where z = H_eff = Hb - 0.5*cum.
// P[i] = (dh_i, mc_i) with dh_i = h_i - h_{i+1} (h_S := 0), mc_i = -0.5*c_i,
// c_i = theta*area*sqrt(2G).  Per iter (3-op chain: max, sqrt, fma):
//   r = sqrt(max(w,0));  q' = mc*r (= -q/2, stored);  w = fma(mc, r, w+dh)
// Final w_S = z_S, so H_new = 2*w_S - Hb (computed by caller).
// Ping-pong register prefetch (32 ahead, ~512 cyc) hides L2/L3 latency.
// ---------------------------------------------------------------------------
__device__ __forceinline__ float scan_bucket(const float2* P, int ps,
                                             float w, float* Q, int qs) {
    float2 A[PF], Bf[PF];
    const float2* Pp = P;
    float* Qp = Q;
    #pragma unroll
    for (int j = 0; j < PF; ++j) A[j] = Pp[(long)j * ps];
    Pp += (long)PF * ps;
    for (int sb = 0; sb < NS; sb += 2 * PF) {
        #pragma unroll
        for (int j = 0; j < PF; ++j) Bf[j] = Pp[(long)j * ps];
        Pp += (long)PF * ps;
        #pragma unroll
        for (int j = 0; j < PF; ++j) {
            float r = __builtin_amdgcn_sqrtf(fmaxf(w, 0.0f));
            Qp[(long)j * qs] = A[j].y * r;       // q' = -q/2 (off-chain)
            w = fmaf(A[j].y, r, w + A[j].x);     // w+dh computed in parallel
        }
        Qp += (long)PF * qs;
        if (sb + 2 * PF < NS) {
            #pragma unroll
            for (int j = 0; j < PF; ++j) A[j] = Pp[(long)j * ps];
            Pp += (long)PF * ps;
        }
        #pragma unroll
        for (int j = 0; j < PF; ++j) {
            float r = __builtin_amdgcn_sqrtf(fmaxf(w, 0.0f));
            Qp[(long)j * qs] = Bf[j].y * r;
            w = fmaf(Bf[j].y, r, w + Bf[j].x);
        }
        Qp += (long)PF * qs;
    }
    return w;
}

// ---------------------------------------------------------------------------
// Precompute: P1 [S][B] transposed (dh,mc) for layer 1 (+ h01 first-heights),
// PL0/h00f for layer-0 bucket 0, P2 (h,c) for layer-2 spigot 0, H-state init,
// and the t=0 layer-0 scan (LDS-local copy, overlapped with the transpose).
// ---------------------------------------------------------------------------
__global__ __launch_bounds__(256, 1) void prep_kernel(
        const float* __restrict__ u,
        const float* __restrict__ theta, const float2* __restrict__ sp,
        const float* __restrict__ H0,
        float2* __restrict__ P1, float2* __restrict__ PL0, float2* __restrict__ P2,
        float* __restrict__ H1, float* __restrict__ H2,
        float* __restrict__ h01, float* __restrict__ H00, float* __restrict__ h00f,
        float* __restrict__ Q0) {
    int blk = blockIdx.x, tid = threadIdx.x;
    if (blk < 1024) {
        // 64x64 tile transpose for layer 1 via padded LDS.
        __shared__ float2 tile[64][65];
        int bt = blk >> 5, st = blk & 31;
        int ls = tid & 63, rb = tid >> 6;
        #pragma unroll 4
        for (int r = 0; r < 16; ++r) {
            int bl = rb + 4 * r;
            int b = bt * 64 + bl, s = st * 64 + ls;
            long idx = (long)(NB + b) * NS + s;            // layer 1
            float2 v = sp[idx];
            float hn = (s == NS - 1) ? 0.0f : sp[idx + 1].x;
            float mc = theta[idx] * v.y * MHALF_SQRT2G;
            tile[bl][ls] = make_float2(v.x - hn, mc);
            if (s == 0) h01[b] = v.x;
        }
        __syncthreads();
        int lb = tid & 63, rs = tid >> 6;
        #pragma unroll 4
        for (int r = 0; r < 16; ++r) {
            int sl = rs + 4 * r;
            int s = st * 64 + sl, b = bt * 64 + lb;
            P1[(long)s * NB + b] = tile[lb][sl];
        }
    } else if (blk < 1032) {
        int s = (blk - 1024) * 256 + tid;                  // 0..2047
        float2 v = sp[s];                                  // layer0 bucket0
        float hn = (s == NS - 1) ? 0.0f : sp[s + 1].x;
        PL0[s] = make_float2(v.x - hn, theta[s] * v.y * MHALF_SQRT2G);
        if (s == 0) *h00f = v.x;
    } else if (blk < 1040) {
        int b = (blk - 1032) * 256 + tid;
        long idx = (long)(2 * NB + b) * NS;                // layer2, spigot 0
        float2 v = sp[idx];
        P2[b] = make_float2(v.x, theta[idx] * v.y * SQRT2G);
    } else if (blk < 1056) {
        int i = (blk - 1040) * 256 + tid;                  // 0..4095
        if (i < NB) H1[i] = H0[NB + i];
        else        H2[i - NB] = H0[2 * NB + (i - NB)];
    } else {
        // layer-0 scan for timestep 0, from an LDS-local (dh,mc) copy
        __shared__ float2 L0[NS];
        for (int j = tid; j < NS; j += 256) {
            float2 v = sp[j];
            float hn = (j == NS - 1) ? 0.0f : sp[j + 1].x;
            L0[j] = make_float2(v.x - hn, theta[j] * v.y * MHALF_SQRT2G);
        }
        __syncthreads();
        if (tid == 0) {
            float Hb = H0[0] + u[0] * (1.0f / 3.0f);
            float w = scan_bucket(L0, 1, Hb - sp[0].x, Q0, 1);
            *H00 = 2.0f * w - Hb;
        }
    }
}

// ---------------------------------------------------------------------------
// Per-timestep kernel, launch k = 0..16:
//   blocks 0..31  : layer-1 solve for timestep k           (k < 16)
//   block  32     : layer-0 scan for timestep k+1          (k+1 < 16)
//   blocks 33..160: column-reduce + layer-2 step for t=k-1 (k >= 1)
// Q double-buffered by timestep parity so reduce(t-1) and L1(t) coexist.
// Q holds q' = -q/2 (consumers apply *-2).
// ---------------------------------------------------------------------------
__global__ __launch_bounds__(64, 1) void step_kernel(
        int k, const float* __restrict__ u,
        const float2* __restrict__ P1, const float2* __restrict__ PL0,
        const float2* __restrict__ P2,
        float* __restrict__ Qa, float* __restrict__ Qb, float* __restrict__ Q0,
        float* __restrict__ H1, float* __restrict__ H2,
        const float* __restrict__ h01, float* __restrict__ H00,
        const float* __restrict__ h00f,
        float* __restrict__ out) {
    int blk = blockIdx.x, tid = threadIdx.x;
    if (blk < 32) {
        if (k >= NT) return;
        int b = blk * 64 + tid;
        float* Qw = (k & 1) ? Qb : Qa;
        float inflow = fmaf(-2.0f, Q0[k * NB + b], u[k] * (1.0f / (3.0f * (float)NB)));
        float Hb = H1[b] + inflow;
        float w = scan_bucket(P1 + b, NB, Hb - h01[b], Qw + b, NB);
        H1[b] = 2.0f * w - Hb;
    } else if (blk == 32) {
        if (k + 1 >= NT) return;
        if (tid == 0) {
            float Hb = *H00 + u[k + 1] * (1.0f / 3.0f);
            float w = scan_bucket(PL0, 1, Hb - *h00f, Q0 + (k + 1) * NB, 1);
            *H00 = 2.0f * w - Hb;
        }
    } else {
        int t = k - 1;
        if (t < 0) return;
        const float* Qr = (t & 1) ? Qb : Qa;
        int r = blk - 33;                                   // 0..127, 16 buckets each
        float ppl_B = u[t] * (1.0f / (3.0f * (float)NB));
        float qacc = 0.0f;
        for (int i = 0; i < 16; ++i) {
            int b = r * 16 + i;
            const float* row = Qr + (long)b * NB;           // sum over upstream buckets
            float s0 = 0.f, s1 = 0.f, s2 = 0.f, s3 = 0.f;
            for (int j = 0; j < NB; j += 256) {
                s0 += row[j + tid];
                s1 += row[j + 64 + tid];
                s2 += row[j + 128 + tid];
                s3 += row[j + 192 + tid];
            }
            float s = (s0 + s1) + (s2 + s3);
            #pragma unroll
            for (int m = 32; m >= 1; m >>= 1) s += __shfl_xor(s, m, 64);
            if (tid == 0) {
                float Hb = H2[b] + fmaf(-2.0f, s, ppl_B);   // undo q' scaling
                float h = fmaxf(Hb - P2[b].x, 0.0f);
                float q = P2[b].y * __builtin_amdgcn_sqrtf(h);
                H2[b] = Hb - q;
                qacc += q;
            }
        }
        if (tid == 0) atomicAdd(out + t, qacc);
    }
}

extern "C" void kernel_launch(void* const* d_in, const int* in_sizes, int n_in,
                              void* d_out, int out_size, void* d_ws, size_t ws_size,
                              hipStream_t stream) {
    const float*  u     = (const float*)d_in[0];
    const float*  theta = (const float*)d_in[1];
    const float2* sp    = (const float2*)d_in[2];   // [L][B][S][2] as float2
    const float*  H0    = (const float*)d_in[3];
    float* out = (float*)d_out;

    // Workspace layout (floats); total ~64.2 MB
    float* ws   = (float*)d_ws;
    float2* P1  = (float2*)ws;                       // 4,194,304 float2 (32 MB)
    float*  Qa  = ws + (size_t)2 * NS * NB;          // 4,194,304 floats (16 MB)
    float*  Qb  = Qa + (size_t)NS * NB;              // 16 MB
    float2* PL0 = (float2*)(Qb + (size_t)NS * NB);   // 2048 float2
    float2* P2  = PL0 + NS;                          // 2048 float2
    float*  Q0  = (float*)(P2 + NB);                 // 16*2048 floats
    float*  H1  = Q0 + (size_t)NT * NB;              // 2048
    float*  H2  = H1 + NB;                           // 2048
    float*  h01 = H2 + NB;                           // 2048
    float*  H00 = h01 + NB;                          // 1
    float*  h00f= H00 + 1;                           // 1

    hipMemsetAsync(d_out, 0, (size_t)out_size * sizeof(float), stream);

    prep_kernel<<<1057, 256, 0, stream>>>(u, theta, sp, H0, P1, PL0, P2,
                                          H1, H2, h01, H00, h00f, Q0);
    for (int k = 0; k <= NT; ++k) {
        step_kernel<<<161, 64, 0, stream>>>(k, u, P1, PL0, P2, Qa, Qb, Q0,
                                            H1, H2, h01, H00, h00f, out);
    }
}

// Round 5
// 1058.969 us; speedup vs baseline: 1.2113x; 1.2113x over previous
//
#include <hip/hip_runtime.h>

// Problem constants (from reference)
#define NB 2048                  // buckets per layer (B)
#define NS 2048                  // spigots per bucket (S)
#define NT 16                    // timesteps
#define SQRT2G 4.4294469f        // sqrt(2*9.81)
#define MHALF_SQRT2G -2.2147234f // -0.5*sqrt(2*9.81)

typedef float f4 __attribute__((ext_vector_type(4)));

// Async global->LDS, 16B per lane: lane l writes lds + l*16. All addresses
// compiler-managed; increments vmcnt (tracked by the compiler's waitcnt pass,
// which can only ADD safety waits on top of our manual ones).
__device__ __forceinline__ void gll16(const f4* g, f4* l) {
    __builtin_amdgcn_global_load_lds(
        (const __attribute__((address_space(1))) unsigned int*)g,
        (__attribute__((address_space(3))) unsigned int*)l, 16, 0, 0);
}

// 4 chained scan iterations from two pair-packed f4 (dh0,mc0,dh1,mc1).
// Chain per iter: r = sqrt(max(w,0)); w = fma(mc, r, w+dh).  q' = mc*r = -q/2.
#define QUAD(p0, p1, QS)                                          \
    {                                                             \
        float r0 = __builtin_amdgcn_sqrtf(fmaxf(w, 0.0f));        \
        float q0 = p0.y * r0; w = fmaf(p0.y, r0, w + p0.x);       \
        float r1 = __builtin_amdgcn_sqrtf(fmaxf(w, 0.0f));        \
        float q1 = p0.w * r1; w = fmaf(p0.w, r1, w + p0.z);       \
        float r2 = __builtin_amdgcn_sqrtf(fmaxf(w, 0.0f));        \
        float q2 = p1.y * r2; w = fmaf(p1.y, r2, w + p1.x);       \
        float r3 = __builtin_amdgcn_sqrtf(fmaxf(w, 0.0f));        \
        float q3 = p1.w * r3; w = fmaf(p1.w, r3, w + p1.z);       \
        f4 qv; qv.x = q0; qv.y = q1; qv.z = q2; qv.w = q3;        \
        qp[(size_t)jj * (QS)] = qv;                               \
    }

// ---------------------------------------------------------------------------
// Simple compiler-scheduled scan (float2 (dh,mc), used once in prep from LDS)
// ---------------------------------------------------------------------------
#define SPF 32
__device__ __forceinline__ float scan_simple(const float2* P, float w, float* Q) {
    float2 A[SPF], Bf[SPF];
    const float2* Pp = P;
    float* Qp = Q;
    #pragma unroll
    for (int j = 0; j < SPF; ++j) A[j] = Pp[j];
    Pp += SPF;
    for (int sb = 0; sb < NS; sb += 2 * SPF) {
        #pragma unroll
        for (int j = 0; j < SPF; ++j) Bf[j] = Pp[j];
        Pp += SPF;
        #pragma unroll
        for (int j = 0; j < SPF; ++j) {
            float r = __builtin_amdgcn_sqrtf(fmaxf(w, 0.0f));
            Qp[j] = A[j].y * r;
            w = fmaf(A[j].y, r, w + A[j].x);
        }
        Qp += SPF;
        if (sb + 2 * SPF < NS) {
            #pragma unroll
            for (int j = 0; j < SPF; ++j) A[j] = Pp[j];
            Pp += SPF;
        }
        #pragma unroll
        for (int j = 0; j < SPF; ++j) {
            float r = __builtin_amdgcn_sqrtf(fmaxf(w, 0.0f));
            Qp[j] = Bf[j].y * r;
            w = fmaf(Bf[j].y, r, w + Bf[j].x);
        }
        Qp += SPF;
    }
    return w;
}

// ---------------------------------------------------------------------------
// Precompute: P1q [s/2][B] float4 pair-packed (dh,mc) for layer 1 (+ h01),
// PL0q pair-packed for layer-0 bucket 0 (+ h00f), P2 (h,c) for layer-2
// spigot 0, H-state init, and the t=0 layer-0 scan (from an LDS copy).
// ---------------------------------------------------------------------------
__global__ __launch_bounds__(256, 1) void prep_kernel(
        const float* __restrict__ u,
        const float* __restrict__ theta, const float2* __restrict__ sp,
        const float* __restrict__ H0,
        f4* __restrict__ P1q, f4* __restrict__ PL0q, float2* __restrict__ P2,
        float* __restrict__ H1, float* __restrict__ H2,
        float* __restrict__ h01, float* __restrict__ H00, float* __restrict__ h00f,
        float* __restrict__ Q0) {
    int blk = blockIdx.x, tid = threadIdx.x;
    if (blk < 1024) {
        // 64x64 tile transpose for layer 1 via padded LDS, pair-packed output.
        __shared__ float2 tile[64][65];
        int bt = blk >> 5, st = blk & 31;
        int ls = tid & 63, rb = tid >> 6;
        #pragma unroll 4
        for (int r = 0; r < 16; ++r) {
            int bl = rb + 4 * r;
            int b = bt * 64 + bl, s = st * 64 + ls;
            long idx = (long)(NB + b) * NS + s;            // layer 1
            float2 v = sp[idx];
            float hn = (s == NS - 1) ? 0.0f : sp[idx + 1].x;
            float mc = theta[idx] * v.y * MHALF_SQRT2G;
            tile[bl][ls] = make_float2(v.x - hn, mc);
            if (s == 0) h01[b] = v.x;
        }
        __syncthreads();
        int lb = tid & 63, rs = tid >> 6;                  // rs in 0..3
        #pragma unroll 4
        for (int r = 0; r < 8; ++r) {
            int sq = rs + 4 * r;                           // local pair-row 0..31
            float2 e0 = tile[lb][2 * sq], e1 = tile[lb][2 * sq + 1];
            f4 val; val.x = e0.x; val.y = e0.y; val.z = e1.x; val.w = e1.y;
            P1q[(size_t)(st * 32 + sq) * NB + bt * 64 + lb] = val;
        }
    } else if (blk < 1028) {
        int pi = (blk - 1024) * 256 + tid;                 // pair idx 0..1023
        int s0 = 2 * pi;
        float2 v0 = sp[s0], v1 = sp[s0 + 1];               // layer0 bucket0
        float h2 = (s0 + 2 < NS) ? sp[s0 + 2].x : 0.0f;
        f4 val;
        val.x = v0.x - v1.x; val.y = theta[s0] * v0.y * MHALF_SQRT2G;
        val.z = v1.x - h2;   val.w = theta[s0 + 1] * v1.y * MHALF_SQRT2G;
        PL0q[pi] = val;
        if (pi == 0) *h00f = v0.x;
    } else if (blk < 1036) {
        int b = (blk - 1028) * 256 + tid;
        long idx = (long)(2 * NB + b) * NS;                // layer2, spigot 0
        float2 v = sp[idx];
        P2[b] = make_float2(v.x, theta[idx] * v.y * SQRT2G);
    } else if (blk < 1052) {
        int i = (blk - 1036) * 256 + tid;                  // 0..4095
        if (i < NB) H1[i] = H0[NB + i];
        else        H2[i - NB] = H0[2 * NB + (i - NB)];
    } else {
        // layer-0 scan for timestep 0, from an LDS-local (dh,mc) copy
        __shared__ float2 L0buf[NS];
        for (int j = tid; j < NS; j += 256) {
            float2 v = sp[j];
            float hn = (j == NS - 1) ? 0.0f : sp[j + 1].x;
            L0buf[j] = make_float2(v.x - hn, theta[j] * v.y * MHALF_SQRT2G);
        }
        __syncthreads();
        if (tid == 0) {
            float Hb = H0[0] + u[0] * (1.0f / 3.0f);
            float w = scan_simple((const float2*)L0buf, Hb - sp[0].x, Q0);
            *H00 = 2.0f * w - Hb;
        }
    }
}

// ---------------------------------------------------------------------------
// Per-timestep kernel, launch k = 0..16 (64 threads = 1 wave per block):
//   blocks 0..31 : layer-1 solve for timestep k           (k < 16)
//   block  32    : layer-0 scan for timestep k+1          (k+1 < 16)
//   blocks 33..64: column-reduce + layer-2 step for t=k-1 (k >= 1)
// Layer-1 pipelining: global_load_lds double-buffer (SA/SB, 16 rows x 64
// lanes x 16B), manual vmcnt(16) between batches.  In-order vmcnt retirement
// + <=40 outstanding ops make the count exact; compiler-added waits can only
// over-wait.  Q double-buffered by parity; holds q' = -q/2 in [s/4][B] f4.
// ---------------------------------------------------------------------------
__global__ __launch_bounds__(64, 1) void step_kernel(
        int k, const float* __restrict__ u,
        const f4* __restrict__ P1q, const f4* __restrict__ PL0q,
        const float2* __restrict__ P2,
        f4* __restrict__ Qa, f4* __restrict__ Qb, float* __restrict__ Q0,
        float* __restrict__ H1, float* __restrict__ H2,
        const float* __restrict__ h01, float* __restrict__ H00,
        const float* __restrict__ h00f,
        float* __restrict__ out) {
    __shared__ f4 SA[16 * 64];
    __shared__ f4 SB[16 * 64];
    int blk = blockIdx.x, lane = threadIdx.x;
    if (blk < 32) {
        if (k >= NT) return;
        int b = blk * 64 + lane;
        f4* Qw = (k & 1) ? Qb : Qa;
        float inflow = fmaf(-2.0f, Q0[k * NB + b], u[k] * (1.0f / (3.0f * (float)NB)));
        float Hb = H1[b] + inflow;
        float w = Hb - h01[b];
        const f4* gp = P1q + b;                  // this lane's bucket column
        // prologue: issue batches 0 (->SA) and 1 (->SB)
        #pragma unroll
        for (int j = 0; j < 16; ++j) gll16(gp + (size_t)j * NB, SA + j * 64);
        gp += (size_t)16 * NB;
        #pragma unroll
        for (int j = 0; j < 16; ++j) gll16(gp + (size_t)j * NB, SB + j * 64);
        gp += (size_t)16 * NB;
        f4* qp = Qw + b;
        for (int ip = 0; ip < 31; ++ip) {
            asm volatile("s_waitcnt vmcnt(16)" ::: "memory");
            __builtin_amdgcn_sched_barrier(0);
            #pragma unroll
            for (int jj = 0; jj < 8; ++jj) {
                f4 p0 = SA[(2 * jj) * 64 + lane], p1 = SA[(2 * jj + 1) * 64 + lane];
                QUAD(p0, p1, NB)
            }
            qp += (size_t)8 * NB;
            #pragma unroll
            for (int j = 0; j < 16; ++j) gll16(gp + (size_t)j * NB, SA + j * 64);
            gp += (size_t)16 * NB;
            asm volatile("s_waitcnt vmcnt(16)" ::: "memory");
            __builtin_amdgcn_sched_barrier(0);
            #pragma unroll
            for (int jj = 0; jj < 8; ++jj) {
                f4 p0 = SB[(2 * jj) * 64 + lane], p1 = SB[(2 * jj + 1) * 64 + lane];
                QUAD(p0, p1, NB)
            }
            qp += (size_t)8 * NB;
            #pragma unroll
            for (int j = 0; j < 16; ++j) gll16(gp + (size_t)j * NB, SB + j * 64);
            gp += (size_t)16 * NB;
        }
        // epilogue: batches 62 (SA; 63's loads still in flight) and 63 (SB)
        asm volatile("s_waitcnt vmcnt(16)" ::: "memory");
        __builtin_amdgcn_sched_barrier(0);
        #pragma unroll
        for (int jj = 0; jj < 8; ++jj) {
            f4 p0 = SA[(2 * jj) * 64 + lane], p1 = SA[(2 * jj + 1) * 64 + lane];
            QUAD(p0, p1, NB)
        }
        qp += (size_t)8 * NB;
        asm volatile("s_waitcnt vmcnt(0)" ::: "memory");
        __builtin_amdgcn_sched_barrier(0);
        #pragma unroll
        for (int jj = 0; jj < 8; ++jj) {
            f4 p0 = SB[(2 * jj) * 64 + lane], p1 = SB[(2 * jj + 1) * 64 + lane];
            QUAD(p0, p1, NB)
        }
        H1[b] = 2.0f * w - Hb;
    } else if (blk == 32) {
        if (k + 1 >= NT) return;
        // stage PL0q (1024 f4 = 16 KB) into SA, identity layout
        #pragma unroll
        for (int j = 0; j < 16; ++j) gll16(PL0q + j * 64 + lane, SA + j * 64);
        asm volatile("s_waitcnt vmcnt(0)" ::: "memory");
        __builtin_amdgcn_sched_barrier(0);
        if (lane == 0) {
            float Hb = *H00 + u[k + 1] * (1.0f / 3.0f);
            float w = Hb - *h00f;
            f4* qp = (f4*)(Q0 + (size_t)(k + 1) * NB);
            for (int bi = 0; bi < 64; ++bi) {
                f4 P[16];
                #pragma unroll
                for (int j = 0; j < 16; ++j) P[j] = SA[bi * 16 + j];
                #pragma unroll
                for (int jj = 0; jj < 8; ++jj) {
                    f4 p0 = P[2 * jj], p1 = P[2 * jj + 1];
                    QUAD(p0, p1, 1)
                }
                qp += 8;
            }
            *H00 = 2.0f * w - Hb;
        }
    } else {
        int t = k - 1;
        if (t < 0) return;
        const f4* Qr = (t & 1) ? Qb : Qa;
        int r = blk - 33;                                   // 0..31: 16 quad-rows
        float ppl_B = u[t] * (1.0f / (3.0f * (float)NB));
        float qacc = 0.0f;
        for (int ql = 0; ql < 16; ++ql) {
            int qr = r * 16 + ql;                           // s-quad index
            const f4* row = Qr + (size_t)qr * NB;
            f4 a0 = {0,0,0,0}, a1 = {0,0,0,0}, a2 = {0,0,0,0}, a3 = {0,0,0,0};
            #pragma unroll
            for (int kk = 0; kk < 32; kk += 4) {
                a0 += row[lane + 64 * kk];
                a1 += row[lane + 64 * (kk + 1)];
                a2 += row[lane + 64 * (kk + 2)];
                a3 += row[lane + 64 * (kk + 3)];
            }
            f4 acc = (a0 + a1) + (a2 + a3);
            #pragma unroll
            for (int m = 32; m >= 1; m >>= 1) {
                acc.x += __shfl_xor(acc.x, m, 64);
                acc.y += __shfl_xor(acc.y, m, 64);
                acc.z += __shfl_xor(acc.z, m, 64);
                acc.w += __shfl_xor(acc.w, m, 64);
            }
            if (lane == 0) {
                float infl[4] = {acc.x, acc.y, acc.z, acc.w};
                #pragma unroll
                for (int c = 0; c < 4; ++c) {
                    int b2 = qr * 4 + c;                    // layer-2 bucket
                    float Hb = H2[b2] + fmaf(-2.0f, infl[c], ppl_B);
                    float h = fmaxf(Hb - P2[b2].x, 0.0f);
                    float q = P2[b2].y * __builtin_amdgcn_sqrtf(h);
                    H2[b2] = Hb - q;
                    qacc += q;
                }
            }
        }
        if (lane == 0) atomicAdd(out + t, qacc);
    }
}

extern "C" void kernel_launch(void* const* d_in, const int* in_sizes, int n_in,
                              void* d_out, int out_size, void* d_ws, size_t ws_size,
                              hipStream_t stream) {
    const float*  u     = (const float*)d_in[0];
    const float*  theta = (const float*)d_in[1];
    const float2* sp    = (const float2*)d_in[2];   // [L][B][S][2] as float2
    const float*  H0    = (const float*)d_in[3];
    float* out = (float*)d_out;

    // Workspace layout (floats); total ~64.3 MB
    float* ws   = (float*)d_ws;
    f4*    P1q  = (f4*)ws;                           // [S/2][B] float4 (32 MB)
    float* Qa_f = ws + (size_t)2 * NS * NB;          // [S/4][B] float4 (16 MB)
    float* Qb_f = Qa_f + (size_t)NS * NB;            // 16 MB
    f4*    PL0q = (f4*)(Qb_f + (size_t)NS * NB);     // NS/2 float4 (16 KB)
    float2* P2  = (float2*)(PL0q + NS / 2);          // 2048 float2
    float* Q0   = (float*)(P2 + NB);                 // 16*2048 floats
    float* H1   = Q0 + (size_t)NT * NB;              // 2048
    float* H2   = H1 + NB;                           // 2048
    float* h01  = H2 + NB;                           // 2048
    float* H00  = h01 + NB;                          // 1
    float* h00f = H00 + 1;                           // 1

    hipMemsetAsync(d_out, 0, (size_t)out_size * sizeof(float), stream);

    prep_kernel<<<1053, 256, 0, stream>>>(u, theta, sp, H0, P1q, PL0q, P2,
                                          H1, H2, h01, H00, h00f, Q0);
    for (int k = 0; k <= NT; ++k) {
        step_kernel<<<65, 64, 0, stream>>>(k, u, P1q, PL0q, P2,
                                           (f4*)Qa_f, (f4*)Qb_f, Q0,
                                           H1, H2, h01, H00, h00f, out);
    }
}